// Round 1
// 1194.409 us; speedup vs baseline: 1.5347x; 1.5347x over previous
//
#include <hip/hip_runtime.h>
#include <hip/hip_bf16.h>

using bf16 = __hip_bfloat16;
typedef __attribute__((ext_vector_type(8))) short bf16x8;   // 8 bf16 = 4 VGPRs
typedef __attribute__((ext_vector_type(4))) float f32x4;

__device__ inline float u2f(unsigned int u) { return __uint_as_float(u << 16); }
__device__ inline float toF(float x) { return x; }
__device__ inline float toF(bf16 x) { return __bfloat162float(x); }
__device__ inline void storeO(float* p, float v) { *p = v; }
__device__ inline void storeO(bf16* p, float v) { *p = __float2bfloat16(v); }

// byte offset into a [64][128B] LDS tile with XOR swizzle (bank-conflict fix)
__device__ inline int swzb(int row, int bcol) {
    return row * 128 + (bcol ^ (((row ^ (row >> 3)) & 7) << 4));
}

// ---------------------------------------------------------------- transpose
// fp32 [R,C] -> bf16 [C,R]. R, C multiples of 32. block = 256 (32x8 logical).
__global__ __launch_bounds__(256) void transpose_k(const float* __restrict__ in,
                                                   bf16* __restrict__ out,
                                                   int R, int C) {
    __shared__ float tile[32][33];
    const int c0 = blockIdx.x * 32, r0 = blockIdx.y * 32;
    const int tx = threadIdx.x & 31, ty = threadIdx.x >> 5;
#pragma unroll
    for (int i = 0; i < 32; i += 8)
        tile[ty + i][tx] = in[(size_t)(r0 + ty + i) * C + (c0 + tx)];
    __syncthreads();
#pragma unroll
    for (int i = 0; i < 32; i += 8)
        out[(size_t)(c0 + ty + i) * R + (r0 + tx)] = __float2bfloat16(tile[tx][ty + i]);
}

// ---------------------------------------------------------------- layernorm
__device__ inline float waveRedSum(float x) {
#pragma unroll
    for (int off = 32; off; off >>= 1) x += __shfl_xor(x, off, 64);
    return x;
}

template <typename T>
__global__ __launch_bounds__(256) void layernorm_k(const T* __restrict__ in,
                                                   const float* __restrict__ g,
                                                   const float* __restrict__ bta,
                                                   bf16* __restrict__ out) {
    const int row = blockIdx.x, t = threadIdx.x;
    const int lane = t & 63, wid = t >> 6;
    const T* xr = in + (size_t)row * 1024;
    float v0, v1, v2, v3;
    if constexpr (sizeof(T) == 4) {
        float4 u = ((const float4*)xr)[t];
        v0 = u.x; v1 = u.y; v2 = u.z; v3 = u.w;
    } else {
        ushort4 u = ((const ushort4*)xr)[t];
        v0 = u2f(u.x); v1 = u2f(u.y); v2 = u2f(u.z); v3 = u2f(u.w);
    }
    __shared__ float red[8];
    float s = waveRedSum(v0 + v1 + v2 + v3);
    if (lane == 0) red[wid] = s;
    __syncthreads();
    float mu = (red[0] + red[1] + red[2] + red[3]) * (1.f / 1024.f);
    float d0 = v0 - mu, d1 = v1 - mu, d2 = v2 - mu, d3 = v3 - mu;
    float ss = waveRedSum(d0 * d0 + d1 * d1 + d2 * d2 + d3 * d3);
    if (lane == 0) red[4 + wid] = ss;
    __syncthreads();
    float var = (red[4] + red[5] + red[6] + red[7]) * (1.f / 1024.f);
    float inv = rsqrtf(var + 1e-6f);
    const int c = t * 4;
    bf16* orow = out + (size_t)row * 1024;
    orow[c + 0] = __float2bfloat16(d0 * inv * g[c + 0] + bta[c + 0]);
    orow[c + 1] = __float2bfloat16(d1 * inv * g[c + 1] + bta[c + 1]);
    orow[c + 2] = __float2bfloat16(d2 * inv * g[c + 2] + bta[c + 2]);
    orow[c + 3] = __float2bfloat16(d3 * inv * g[c + 3] + bta[c + 3]);
}

// ---------------------------------------------------------------- MFMA GEMM
// C[M,N] = A[M,K](bf16) @ B + bias. 128x128 tile/block, 256 thr = 2x2 waves
// of 64x64 (4x4 mfma_f32_16x16x32_bf16). LDS: As[m][32k], Bs[n][32k] bf16.
// BSRC=0: B fp32 [K,N] row-stride ldB (transpose-convert staged in-kernel).
// BSRC=1: B bf16 [N,K] row-stride ldB (pre-transposed; vector staged).
// Fragment mapping cross-validated (r2 vs r3 bit-identical results).
template <int BSRC, int GELU, int RES, int ACC, typename RT, typename OT>
__global__ __launch_bounds__(256) void mgemm_k(const bf16* __restrict__ A,
                                               const void* __restrict__ Bv, int ldB,
                                               const float* __restrict__ bias,
                                               const RT* __restrict__ resid,
                                               OT* C, int M, int N, int K) {
    __shared__ bf16 As[128 * 32];
    __shared__ bf16 Bs[128 * 32];
    const int tid = threadIdx.x;
    const int lane = tid & 63, wid = tid >> 6;
    const int l16 = lane & 15, quad = lane >> 4;
    const int wm = (wid >> 1) * 64, wn = (wid & 1) * 64;
    const int m0 = blockIdx.y * 128, n0 = blockIdx.x * 128;
    f32x4 acc[4][4] = {};
    for (int k0 = 0; k0 < K; k0 += 32) {
        __syncthreads();
        // stage A: 512 chunks of 8 bf16 (16B); thread does chunks tid, tid+256
#pragma unroll
        for (int p = 0; p < 2; ++p) {
            const int c = tid + p * 256;
            const int r = c >> 2, ch = (c & 3) * 8;
            *(uint4*)&As[r * 32 + ch] =
                *(const uint4*)(A + (size_t)(m0 + r) * K + k0 + ch);
        }
        if (BSRC == 0) {
            // B fp32 [K,N]: 1024 float4 chunks; transpose-convert into Bs[n][k]
            const float* B = (const float*)Bv;
#pragma unroll
            for (int p = 0; p < 4; ++p) {
                const int c = tid + p * 256;
                const int k = c >> 5, nc = (c & 31) * 4;
                float4 f = *(const float4*)(B + (size_t)(k0 + k) * ldB + n0 + nc);
                Bs[(nc + 0) * 32 + k] = __float2bfloat16(f.x);
                Bs[(nc + 1) * 32 + k] = __float2bfloat16(f.y);
                Bs[(nc + 2) * 32 + k] = __float2bfloat16(f.z);
                Bs[(nc + 3) * 32 + k] = __float2bfloat16(f.w);
            }
        } else {
            // B bf16 [N,K]: mirror of A staging
            const bf16* B = (const bf16*)Bv;
#pragma unroll
            for (int p = 0; p < 2; ++p) {
                const int c = tid + p * 256;
                const int r = c >> 2, ch = (c & 3) * 8;
                *(uint4*)&Bs[r * 32 + ch] =
                    *(const uint4*)(B + (size_t)(n0 + r) * ldB + k0 + ch);
            }
        }
        __syncthreads();
        bf16x8 a[4], b[4];
#pragma unroll
        for (int i = 0; i < 4; ++i)
            a[i] = *(const bf16x8*)&As[(wm + i * 16 + l16) * 32 + quad * 8];
#pragma unroll
        for (int i = 0; i < 4; ++i)
            b[i] = *(const bf16x8*)&Bs[(wn + i * 16 + l16) * 32 + quad * 8];
#pragma unroll
        for (int mi = 0; mi < 4; ++mi)
#pragma unroll
            for (int ni = 0; ni < 4; ++ni)
                acc[mi][ni] = __builtin_amdgcn_mfma_f32_16x16x32_bf16(
                    a[mi], b[ni], acc[mi][ni], 0, 0, 0);
    }
#pragma unroll
    for (int mi = 0; mi < 4; ++mi) {
#pragma unroll
        for (int ni = 0; ni < 4; ++ni) {
            const int col = n0 + wn + ni * 16 + l16;
            const float bv = ACC ? 0.f : bias[col];
#pragma unroll
            for (int r = 0; r < 4; ++r) {
                const int row = m0 + wm + mi * 16 + quad * 4 + r;
                float val = acc[mi][ni][r] + bv;
                if (GELU) {
                    float z = 0.7978845608028654f * (val + 0.044715f * val * val * val);
                    float th = 1.f - 2.f / (__expf(2.f * z) + 1.f);
                    val = 0.5f * val * (1.f + th);
                }
                const size_t idx = (size_t)row * N + col;
                if (RES) val += toF(resid[idx]);
                if (ACC) val += toF(C[idx]);
                storeO(&C[idx], val);
            }
        }
    }
}

// ---------------------------------------------------------------- attention
// MFMA flash attention. q,k,v,o: [8,1024,16,64] bf16. Block = 256 thr = 4
// waves; each wave owns 64 q-rows x D=64 output. Per 64-key tile:
//   S^T = K @ Q^T  (mfma, A=K-frag from LDS, B=Q-frag in regs)
//     -> C layout: row = k (quad*4+r), col = q (l16): row-softmax over k is a
//        16-value local reduce + shfl_xor(16,32) across quads.
//   online softmax (running m,l per q held per-lane in S^T layout)
//   P -> per-wave LDS [q][k] bf16 (b64 packed writes; k-contiguous per lane)
//   O += P @ V via mfma; V staged TRANSPOSED in LDS (Vt[d][k]) so B-frags are
//   contiguous b128 reads. All LDS tiles XOR-swizzled (32-way conflict fix).
// Rescale factors / final l redistributed to O's C-layout via 64-float LDS.
__global__ __launch_bounds__(256) void attn_k(const bf16* __restrict__ q,
                                              const bf16* __restrict__ k,
                                              const bf16* __restrict__ v,
                                              bf16* __restrict__ o) {
    const int b = blockIdx.z, h = blockIdx.y;
    const int qblock = blockIdx.x * 256;
    const int tid = threadIdx.x;
    const int wave = tid >> 6, lane = tid & 63;
    const int l16 = lane & 15, quad = lane >> 4;
    const int q0w = qblock + wave * 64;

    __shared__ __align__(16) bf16 Kl[64 * 64];       // [k][d] swizzled
    __shared__ __align__(16) bf16 Vt[64 * 64];       // [d][k] swizzled
    __shared__ __align__(16) bf16 Pl[4 * 64 * 64];   // per-wave [q][k] swizzled
    __shared__ __align__(16) float sc[4][64];        // per-wave per-q scratch

    // Q fragments (registers): B-frag for S^T. qf[ni][kc]: q-row = ni*16+l16,
    // d-slice = kc*32 + quad*8.
    bf16x8 qf[4][2];
#pragma unroll
    for (int ni = 0; ni < 4; ++ni) {
        const int row = q0w + ni * 16 + l16;
        const bf16* qp = q + (((size_t)b * 1024 + row) * 16 + h) * 64;
#pragma unroll
        for (int kc = 0; kc < 2; ++kc)
            qf[ni][kc] = *(const bf16x8*)(qp + kc * 32 + quad * 8);
    }

    f32x4 acc[4][4] = {};     // O: row q = mi*16+quad*4+r, col d = ni*16+l16
    float mrun[4], lrun[4];   // per q = ni*16+l16 (all quads redundant)
#pragma unroll
    for (int ni = 0; ni < 4; ++ni) { mrun[ni] = -1e30f; lrun[ni] = 0.f; }

    const int NT = blockIdx.x * 4 + 4;          // block tile count
    const int myNT = blockIdx.x * 4 + wave + 1; // this wave's tile count
    for (int t = 0; t < NT; ++t) {
        const int j0 = t * 64;
        __syncthreads();
        // ---- stage K tile row-major (swizzled): 512 x 16B chunks ----
        {
            const int r = tid >> 3, ch = tid & 7;
#pragma unroll
            for (int p = 0; p < 2; ++p) {
                const int row = r + p * 32;
                const size_t g = (((size_t)b * 1024 + j0 + row) * 16 + h) * 64 + ch * 8;
                *(uint4*)((char*)Kl + swzb(row, ch * 16)) = *(const uint4*)(k + g);
            }
        }
        // ---- stage V TRANSPOSED (Vt[d][k], swizzled): thread packs 2 k-rows
        // x 8 d into 8 b32 writes (pair of bf16 along k) ----
        {
            const int r = (tid >> 3) * 2;           // k-row pair
            const int dbase = (tid & 7) * 8;
            const size_t g0 = (((size_t)b * 1024 + j0 + r) * 16 + h) * 64 + dbase;
            const uint4 A4 = *(const uint4*)(v + g0);
            const uint4 B4 = *(const uint4*)(v + g0 + 1024);
            const unsigned aw[4] = {A4.x, A4.y, A4.z, A4.w};
            const unsigned bw[4] = {B4.x, B4.y, B4.z, B4.w};
#pragma unroll
            for (int j = 0; j < 8; ++j) {
                const unsigned lo = (aw[j >> 1] >> ((j & 1) * 16)) & 0xffffu;
                const unsigned hi = (bw[j >> 1] >> ((j & 1) * 16)) & 0xffffu;
                *(unsigned*)((char*)Vt + swzb(dbase + j, r * 2)) = lo | (hi << 16);
            }
        }
        __syncthreads();
        if (t < myNT) {
            // ---- S^T = K @ Q^T ----
            f32x4 st[4][4] = {};
#pragma unroll
            for (int kc = 0; kc < 2; ++kc) {
                bf16x8 kf[4];
#pragma unroll
                for (int mi = 0; mi < 4; ++mi)
                    kf[mi] = *(const bf16x8*)((char*)Kl +
                             swzb(mi * 16 + l16, kc * 64 + quad * 16));
#pragma unroll
                for (int mi = 0; mi < 4; ++mi)
#pragma unroll
                    for (int ni = 0; ni < 4; ++ni)
                        st[mi][ni] = __builtin_amdgcn_mfma_f32_16x16x32_bf16(
                            kf[mi], qf[ni][kc], st[mi][ni], 0, 0, 0);
            }
            // ---- causal mask (diagonal tile only) ----
            if (j0 == q0w) {
#pragma unroll
                for (int mi = 0; mi < 4; ++mi)
#pragma unroll
                    for (int ni = 0; ni < 4; ++ni)
#pragma unroll
                        for (int r = 0; r < 4; ++r)
                            if (mi * 16 + quad * 4 + r > ni * 16 + l16)
                                st[mi][ni][r] = -1e30f;
            }
            // ---- online softmax (scale 1/8 folded into exp) ----
            float fac[4];
#pragma unroll
            for (int ni = 0; ni < 4; ++ni) {
                float mx = -1e30f;
#pragma unroll
                for (int mi = 0; mi < 4; ++mi)
#pragma unroll
                    for (int r = 0; r < 4; ++r) mx = fmaxf(mx, st[mi][ni][r]);
                mx = fmaxf(mx, __shfl_xor(mx, 16, 64));
                mx = fmaxf(mx, __shfl_xor(mx, 32, 64));
                const float nm = fmaxf(mrun[ni], mx);
                fac[ni] = __expf((mrun[ni] - nm) * 0.125f);
                mrun[ni] = nm;
                float ls = 0.f;
#pragma unroll
                for (int mi = 0; mi < 4; ++mi)
#pragma unroll
                    for (int r = 0; r < 4; ++r) {
                        const float p = __expf((st[mi][ni][r] - nm) * 0.125f);
                        st[mi][ni][r] = p;
                        ls += p;
                    }
                ls += __shfl_xor(ls, 16, 64);
                ls += __shfl_xor(ls, 32, 64);
                lrun[ni] = lrun[ni] * fac[ni] + ls;
            }
            // ---- redistribute rescale factors to O layout; rescale O ----
            if (quad == 0)
#pragma unroll
                for (int ni = 0; ni < 4; ++ni) sc[wave][ni * 16 + l16] = fac[ni];
#pragma unroll
            for (int mi = 0; mi < 4; ++mi) {
                const f32x4 f4 = *(const f32x4*)&sc[wave][mi * 16 + quad * 4];
#pragma unroll
                for (int ni = 0; ni < 4; ++ni)
#pragma unroll
                    for (int r = 0; r < 4; ++r) acc[mi][ni][r] *= f4[r];
            }
            // ---- write P to per-wave LDS [q][k] (b64 packed, swizzled) ----
            char* Pb = (char*)Pl + wave * 8192;
#pragma unroll
            for (int ni = 0; ni < 4; ++ni) {
                const int qrow = ni * 16 + l16;
#pragma unroll
                for (int mi = 0; mi < 4; ++mi) {
                    union { bf16 bv[4]; uint2 u2; } pk;
#pragma unroll
                    for (int r = 0; r < 4; ++r)
                        pk.bv[r] = __float2bfloat16(st[mi][ni][r]);
                    *(uint2*)(Pb + swzb(qrow, mi * 32 + quad * 8)) = pk.u2;
                }
            }
            // ---- O += P @ V ----
#pragma unroll
            for (int kc = 0; kc < 2; ++kc) {
                bf16x8 pf[4], vf[4];
#pragma unroll
                for (int mi = 0; mi < 4; ++mi)
                    pf[mi] = *(const bf16x8*)(Pb +
                             swzb(mi * 16 + l16, kc * 64 + quad * 16));
#pragma unroll
                for (int ni = 0; ni < 4; ++ni)
                    vf[ni] = *(const bf16x8*)((char*)Vt +
                             swzb(ni * 16 + l16, kc * 64 + quad * 16));
#pragma unroll
                for (int mi = 0; mi < 4; ++mi)
#pragma unroll
                    for (int ni = 0; ni < 4; ++ni)
                        acc[mi][ni] = __builtin_amdgcn_mfma_f32_16x16x32_bf16(
                            pf[mi], vf[ni], acc[mi][ni], 0, 0, 0);
            }
        }
    }
    // ---- final normalize + store ----
    if (quad == 0)
#pragma unroll
        for (int ni = 0; ni < 4; ++ni) sc[wave][ni * 16 + l16] = lrun[ni];
#pragma unroll
    for (int mi = 0; mi < 4; ++mi) {
        const f32x4 l4 = *(const f32x4*)&sc[wave][mi * 16 + quad * 4];
#pragma unroll
        for (int r = 0; r < 4; ++r) {
            const float inv = 1.f / l4[r];
            const int row = q0w + mi * 16 + quad * 4 + r;
            bf16* orow = o + (((size_t)b * 1024 + row) * 16 + h) * 64;
#pragma unroll
            for (int ni = 0; ni < 4; ++ni)
                orow[ni * 16 + l16] = __float2bfloat16(acc[mi][ni][r] * inv);
        }
    }
}

// ---------------------------------------------------------------- launch
extern "C" void kernel_launch(void* const* d_in, const int* in_sizes, int n_in,
                              void* d_out, int out_size, void* d_ws, size_t ws_size,
                              hipStream_t stream) {
    (void)out_size; (void)ws_size;
    const float* x = (const float*)d_in[0];
    const int base = (n_in >= 18 && in_sizes[1] > 4096) ? 2 : 1;  // skip mask
    const float* ln1s = (const float*)d_in[base + 0];
    const float* ln1b = (const float*)d_in[base + 1];
    const float* wq   = (const float*)d_in[base + 2];
    const float* bq   = (const float*)d_in[base + 3];
    const float* wk   = (const float*)d_in[base + 4];
    const float* bk   = (const float*)d_in[base + 5];
    const float* wv   = (const float*)d_in[base + 6];
    const float* bv   = (const float*)d_in[base + 7];
    const float* wo   = (const float*)d_in[base + 8];
    const float* bo   = (const float*)d_in[base + 9];
    const float* ln2s = (const float*)d_in[base + 10];
    const float* ln2b = (const float*)d_in[base + 11];
    const float* w1   = (const float*)d_in[base + 12];
    const float* b1   = (const float*)d_in[base + 13];
    const float* w2   = (const float*)d_in[base + 14];
    const float* b2   = (const float*)d_in[base + 15];
    float* out = (float*)d_out;   // fp32 output

    // Workspace (peak 64MB), phase-disjoint lifetimes:
    //   [0,16)   h (LN1)            -> ao (attn out)   -> f1c (FFN1 slice)
    //   [16,32)  qb                 -> x2 (residual2, live till end)
    //   [32,48)  kb                 -> h2 (LN2 out)
    //   [48,64)  vb                 -> w1T[48,56) + w2T[56,64)
    char* ws = (char*)d_ws;
    const size_t MB = 1u << 20;
    bf16* h   = (bf16*)(ws + 0 * MB);
    bf16* qb  = (bf16*)(ws + 16 * MB);
    bf16* kb  = (bf16*)(ws + 32 * MB);
    bf16* vb  = (bf16*)(ws + 48 * MB);
    bf16* ao  = (bf16*)(ws + 0 * MB);
    bf16* x2  = (bf16*)(ws + 16 * MB);
    bf16* h2  = (bf16*)(ws + 32 * MB);
    bf16* w1T = (bf16*)(ws + 48 * MB);   // [4096][1024] bf16, 8MB
    bf16* w2T = (bf16*)(ws + 56 * MB);   // [1024][4096] bf16, 8MB
    bf16* f1c = (bf16*)(ws + 0 * MB);

    const dim3 tb(256);
    const dim3 gD(8, 64);   // 1024/128, 8192/128

    layernorm_k<float><<<8192, tb, 0, stream>>>(x, ln1s, ln1b, h);
    mgemm_k<0, 0, 0, 0, float, bf16><<<gD, tb, 0, stream>>>(h, wq, 1024, bq, nullptr, qb, 8192, 1024, 1024);
    mgemm_k<0, 0, 0, 0, float, bf16><<<gD, tb, 0, stream>>>(h, wk, 1024, bk, nullptr, kb, 8192, 1024, 1024);
    mgemm_k<0, 0, 0, 0, float, bf16><<<gD, tb, 0, stream>>>(h, wv, 1024, bv, nullptr, vb, 8192, 1024, 1024);
    attn_k<<<dim3(4, 16, 8), tb, 0, stream>>>(qb, kb, vb, ao);
    // vb dead after attn: transpose FFN weights into [48,64)
    transpose_k<<<dim3(128, 32), tb, 0, stream>>>(w1, w1T, 1024, 4096);
    transpose_k<<<dim3(32, 128), tb, 0, stream>>>(w2, w2T, 4096, 1024);
    mgemm_k<0, 0, 1, 0, float, bf16><<<gD, tb, 0, stream>>>(ao, wo, 1024, bo, x, x2, 8192, 1024, 1024);
    layernorm_k<bf16><<<8192, tb, 0, stream>>>(x2, ln2s, ln2b, h2);
    // FFN chunked over D_FF: 4 slices of 1024; w1T rows / w2T k-columns
    for (int c = 0; c < 4; ++c) {
        mgemm_k<1, 1, 0, 0, float, bf16><<<gD, tb, 0, stream>>>(
            h2, w1T + (size_t)c * 1024 * 1024, 1024, b1 + c * 1024, nullptr, f1c, 8192, 1024, 1024);
        if (c == 0)
            mgemm_k<1, 0, 1, 0, bf16, float><<<gD, tb, 0, stream>>>(
                f1c, w2T + c * 1024, 4096, b2, x2, out, 8192, 1024, 1024);
        else
            mgemm_k<1, 0, 0, 1, bf16, float><<<gD, tb, 0, stream>>>(
                f1c, w2T + c * 1024, 4096, nullptr, nullptr, out, 8192, 1024, 1024);
    }
}

// Round 2
// 698.458 us; speedup vs baseline: 2.6245x; 1.7101x over previous
//
#include <hip/hip_runtime.h>
#include <hip/hip_bf16.h>

using bf16 = __hip_bfloat16;
typedef __attribute__((ext_vector_type(8))) short bf16x8;   // 8 bf16 = 4 VGPRs
typedef __attribute__((ext_vector_type(4))) float f32x4;

__device__ inline float u2f(unsigned int u) { return __uint_as_float(u << 16); }
__device__ inline float toF(float x) { return x; }
__device__ inline float toF(bf16 x) { return __bfloat162float(x); }
__device__ inline void storeO(float* p, float v) { *p = v; }
__device__ inline void storeO(bf16* p, float v) { *p = __float2bfloat16(v); }

// async global->LDS, 16B per lane. LDS dest must be wave-uniform base
// (HW adds lane*16); global src is per-lane.
__device__ inline void gload_lds16(const void* g, void* l) {
    __builtin_amdgcn_global_load_lds(
        (const __attribute__((address_space(1))) void*)g,
        (__attribute__((address_space(3))) void*)l, 16, 0, 0);
}

// byte offset into a [64][128B] LDS tile with XOR swizzle (attn tiles)
__device__ inline int swzb(int row, int bcol) {
    return row * 128 + (bcol ^ (((row ^ (row >> 3)) & 7) << 4));
}

// ---------------------------------------------------------------- transpose
// fp32 [R,C] -> bf16 [C,R]. R, C multiples of 32. block = 256 (32x8 logical).
__global__ __launch_bounds__(256) void transpose_k(const float* __restrict__ in,
                                                   bf16* __restrict__ out,
                                                   int R, int C) {
    __shared__ float tile[32][33];
    const int c0 = blockIdx.x * 32, r0 = blockIdx.y * 32;
    const int tx = threadIdx.x & 31, ty = threadIdx.x >> 5;
#pragma unroll
    for (int i = 0; i < 32; i += 8)
        tile[ty + i][tx] = in[(size_t)(r0 + ty + i) * C + (c0 + tx)];
    __syncthreads();
#pragma unroll
    for (int i = 0; i < 32; i += 8)
        out[(size_t)(c0 + ty + i) * R + (r0 + tx)] = __float2bfloat16(tile[tx][ty + i]);
}

// concat 3x1024 fp32 biases -> [3072]
__global__ __launch_bounds__(256) void catb_k(const float* __restrict__ a,
                                              const float* __restrict__ b,
                                              const float* __restrict__ c,
                                              float* __restrict__ o) {
    const int t = blockIdx.x * 256 + threadIdx.x;
    const float* s = t < 1024 ? a : (t < 2048 ? b : c);
    o[t] = s[t & 1023];
}

// ---------------------------------------------------------------- layernorm
__device__ inline float waveRedSum(float x) {
#pragma unroll
    for (int off = 32; off; off >>= 1) x += __shfl_xor(x, off, 64);
    return x;
}

template <typename T>
__global__ __launch_bounds__(256) void layernorm_k(const T* __restrict__ in,
                                                   const float* __restrict__ g,
                                                   const float* __restrict__ bta,
                                                   bf16* __restrict__ out) {
    const int row = blockIdx.x, t = threadIdx.x;
    const int lane = t & 63, wid = t >> 6;
    const T* xr = in + (size_t)row * 1024;
    float v0, v1, v2, v3;
    if constexpr (sizeof(T) == 4) {
        float4 u = ((const float4*)xr)[t];
        v0 = u.x; v1 = u.y; v2 = u.z; v3 = u.w;
    } else {
        ushort4 u = ((const ushort4*)xr)[t];
        v0 = u2f(u.x); v1 = u2f(u.y); v2 = u2f(u.z); v3 = u2f(u.w);
    }
    __shared__ float red[8];
    float s = waveRedSum(v0 + v1 + v2 + v3);
    if (lane == 0) red[wid] = s;
    __syncthreads();
    float mu = (red[0] + red[1] + red[2] + red[3]) * (1.f / 1024.f);
    float d0 = v0 - mu, d1 = v1 - mu, d2 = v2 - mu, d3 = v3 - mu;
    float ss = waveRedSum(d0 * d0 + d1 * d1 + d2 * d2 + d3 * d3);
    if (lane == 0) red[4 + wid] = ss;
    __syncthreads();
    float var = (red[4] + red[5] + red[6] + red[7]) * (1.f / 1024.f);
    float inv = rsqrtf(var + 1e-6f);
    const int c = t * 4;
    bf16* orow = out + (size_t)row * 1024;
    orow[c + 0] = __float2bfloat16(d0 * inv * g[c + 0] + bta[c + 0]);
    orow[c + 1] = __float2bfloat16(d1 * inv * g[c + 1] + bta[c + 1]);
    orow[c + 2] = __float2bfloat16(d2 * inv * g[c + 2] + bta[c + 2]);
    orow[c + 3] = __float2bfloat16(d3 * inv * g[c + 3] + bta[c + 3]);
}

// ---------------------------------------------------------------- MFMA GEMM
// C[M,N] = A[M,K](bf16,[M][K]) @ B(bf16,[N][K] row-stride ldB) + bias.
// 128x128 tile/block, 256 thr = 2x2 waves of 64x64 (4x4 mfma 16x16x32).
// Staging via global_load_lds width=16: LDS is LINEAR in slot index
// (slot s -> byte s*16; row = s>>2); the k-chunk each slot holds is
// XOR-permuted at the GLOBAL source (lc = (s&3) ^ ((s>>3)&3)) so the
// fragment ds_read_b128 (chunk = quad ^ ((l16>>1)&3)) lands 2-way (free)
// instead of 8-way on the 64B-row layout. Both-sides swizzle (rule #21).
template <int GELU, int RES, int ACC, typename RT, typename OT>
__global__ __launch_bounds__(256) void mgemm_k(const bf16* __restrict__ A,
                                               const bf16* __restrict__ B, int ldB,
                                               const float* __restrict__ bias,
                                               const RT* __restrict__ resid,
                                               OT* C, int M, int N, int K) {
    __shared__ bf16 As[128 * 32];
    __shared__ bf16 Bs[128 * 32];
    const int tid = threadIdx.x;
    const int lane = tid & 63, wid = tid >> 6;
    const int l16 = lane & 15, quad = lane >> 4;
    const int wm = (wid >> 1) * 64, wn = (wid & 1) * 64;
    const int m0 = blockIdx.y * 128, n0 = blockIdx.x * 128;

    const int r0 = tid >> 2, sc0 = tid & 3;
    const int lc0 = sc0 ^ ((r0 >> 1) & 3);
    const int r1 = r0 + 64;
    const int lc1 = sc0 ^ ((r1 >> 1) & 3);
    const bf16* gA0 = A + (size_t)(m0 + r0) * K + lc0 * 8;
    const bf16* gA1 = A + (size_t)(m0 + r1) * K + lc1 * 8;
    const bf16* gB0 = B + (size_t)(n0 + r0) * ldB + lc0 * 8;
    const bf16* gB1 = B + (size_t)(n0 + r1) * ldB + lc1 * 8;
    char* asb = (char*)As;
    char* bsb = (char*)Bs;
    const int lb0 = wid * 1024, lb1 = 4096 + wid * 1024;  // wave-uniform bases
    const int rdsw = (quad ^ ((l16 >> 1) & 3)) * 16;      // frag-read swizzle

    f32x4 acc[4][4] = {};
    for (int k0 = 0; k0 < K; k0 += 32) {
        __syncthreads();
        gload_lds16(gA0 + k0, asb + lb0);
        gload_lds16(gA1 + k0, asb + lb1);
        gload_lds16(gB0 + k0, bsb + lb0);
        gload_lds16(gB1 + k0, bsb + lb1);
        __syncthreads();
        bf16x8 a[4], b[4];
#pragma unroll
        for (int i = 0; i < 4; ++i)
            a[i] = *(const bf16x8*)(asb + (wm + i * 16 + l16) * 64 + rdsw);
#pragma unroll
        for (int i = 0; i < 4; ++i)
            b[i] = *(const bf16x8*)(bsb + (wn + i * 16 + l16) * 64 + rdsw);
#pragma unroll
        for (int mi = 0; mi < 4; ++mi)
#pragma unroll
            for (int ni = 0; ni < 4; ++ni)
                acc[mi][ni] = __builtin_amdgcn_mfma_f32_16x16x32_bf16(
                    a[mi], b[ni], acc[mi][ni], 0, 0, 0);
    }
#pragma unroll
    for (int mi = 0; mi < 4; ++mi) {
#pragma unroll
        for (int ni = 0; ni < 4; ++ni) {
            const int col = n0 + wn + ni * 16 + l16;
            const float bv = bias ? bias[col] : 0.f;
#pragma unroll
            for (int r = 0; r < 4; ++r) {
                const int row = m0 + wm + mi * 16 + quad * 4 + r;
                float val = acc[mi][ni][r] + bv;
                if (GELU) {
                    float z = 0.7978845608028654f * (val + 0.044715f * val * val * val);
                    float th = 1.f - 2.f / (__expf(2.f * z) + 1.f);
                    val = 0.5f * val * (1.f + th);
                }
                const size_t idx = (size_t)row * N + col;
                if (RES) val += toF(resid[idx]);
                if (ACC) val += toF(C[idx]);
                storeO(&C[idx], val);
            }
        }
    }
}

// ---------------------------------------------------------------- attention
// MFMA flash attention. q,k,v: [8,1024,16,64] bf16 views with row stride rs
// (qkv packed [8192][3072] -> rs=3072); o: [8,1024,16,64] (stride 1024).
// Block = 256 thr = 4 waves; each wave owns 64 q-rows x D=64 output.
__global__ __launch_bounds__(256) void attn_k(const bf16* __restrict__ q,
                                              const bf16* __restrict__ k,
                                              const bf16* __restrict__ v,
                                              bf16* __restrict__ o, int rs) {
    const int b = blockIdx.z, h = blockIdx.y;
    const int qblock = blockIdx.x * 256;
    const int tid = threadIdx.x;
    const int wave = tid >> 6, lane = tid & 63;
    const int l16 = lane & 15, quad = lane >> 4;
    const int q0w = qblock + wave * 64;

    __shared__ __align__(16) bf16 Kl[64 * 64];       // [k][d] swizzled
    __shared__ __align__(16) bf16 Vt[64 * 64];       // [d][k] swizzled
    __shared__ __align__(16) bf16 Pl[4 * 64 * 64];   // per-wave [q][k] swizzled
    __shared__ __align__(16) float sc[4][64];        // per-wave per-q scratch

    bf16x8 qf[4][2];
#pragma unroll
    for (int ni = 0; ni < 4; ++ni) {
        const int row = q0w + ni * 16 + l16;
        const bf16* qp = q + ((size_t)b * 1024 + row) * rs + h * 64;
#pragma unroll
        for (int kc = 0; kc < 2; ++kc)
            qf[ni][kc] = *(const bf16x8*)(qp + kc * 32 + quad * 8);
    }

    f32x4 acc[4][4] = {};     // O: row q = mi*16+quad*4+r, col d = ni*16+l16
    float mrun[4], lrun[4];
#pragma unroll
    for (int ni = 0; ni < 4; ++ni) { mrun[ni] = -1e30f; lrun[ni] = 0.f; }

    const int NT = blockIdx.x * 4 + 4;
    const int myNT = blockIdx.x * 4 + wave + 1;
    for (int t = 0; t < NT; ++t) {
        const int j0 = t * 64;
        __syncthreads();
        {   // stage K tile row-major (swizzled)
            const int r = tid >> 3, ch = tid & 7;
#pragma unroll
            for (int p = 0; p < 2; ++p) {
                const int row = r + p * 32;
                const size_t g = ((size_t)b * 1024 + j0 + row) * rs + h * 64 + ch * 8;
                *(uint4*)((char*)Kl + swzb(row, ch * 16)) = *(const uint4*)(k + g);
            }
        }
        {   // stage V transposed (Vt[d][k], swizzled)
            const int r = (tid >> 3) * 2;
            const int dbase = (tid & 7) * 8;
            const size_t g0 = ((size_t)b * 1024 + j0 + r) * rs + h * 64 + dbase;
            const uint4 A4 = *(const uint4*)(v + g0);
            const uint4 B4 = *(const uint4*)(v + g0 + rs);
            const unsigned aw[4] = {A4.x, A4.y, A4.z, A4.w};
            const unsigned bw[4] = {B4.x, B4.y, B4.z, B4.w};
#pragma unroll
            for (int j = 0; j < 8; ++j) {
                const unsigned lo = (aw[j >> 1] >> ((j & 1) * 16)) & 0xffffu;
                const unsigned hi = (bw[j >> 1] >> ((j & 1) * 16)) & 0xffffu;
                *(unsigned*)((char*)Vt + swzb(dbase + j, r * 2)) = lo | (hi << 16);
            }
        }
        __syncthreads();
        if (t < myNT) {
            // S^T = K @ Q^T
            f32x4 st[4][4] = {};
#pragma unroll
            for (int kc = 0; kc < 2; ++kc) {
                bf16x8 kf[4];
#pragma unroll
                for (int mi = 0; mi < 4; ++mi)
                    kf[mi] = *(const bf16x8*)((char*)Kl +
                             swzb(mi * 16 + l16, kc * 64 + quad * 16));
#pragma unroll
                for (int mi = 0; mi < 4; ++mi)
#pragma unroll
                    for (int ni = 0; ni < 4; ++ni)
                        st[mi][ni] = __builtin_amdgcn_mfma_f32_16x16x32_bf16(
                            kf[mi], qf[ni][kc], st[mi][ni], 0, 0, 0);
            }
            if (j0 == q0w) {  // causal mask, diagonal tile only
#pragma unroll
                for (int mi = 0; mi < 4; ++mi)
#pragma unroll
                    for (int ni = 0; ni < 4; ++ni)
#pragma unroll
                        for (int r = 0; r < 4; ++r)
                            if (mi * 16 + quad * 4 + r > ni * 16 + l16)
                                st[mi][ni][r] = -1e30f;
            }
            // online softmax (1/8 scale folded into exp)
            float fac[4];
#pragma unroll
            for (int ni = 0; ni < 4; ++ni) {
                float mx = -1e30f;
#pragma unroll
                for (int mi = 0; mi < 4; ++mi)
#pragma unroll
                    for (int r = 0; r < 4; ++r) mx = fmaxf(mx, st[mi][ni][r]);
                mx = fmaxf(mx, __shfl_xor(mx, 16, 64));
                mx = fmaxf(mx, __shfl_xor(mx, 32, 64));
                const float nm = fmaxf(mrun[ni], mx);
                fac[ni] = __expf((mrun[ni] - nm) * 0.125f);
                mrun[ni] = nm;
                float ls = 0.f;
#pragma unroll
                for (int mi = 0; mi < 4; ++mi)
#pragma unroll
                    for (int r = 0; r < 4; ++r) {
                        const float p = __expf((st[mi][ni][r] - nm) * 0.125f);
                        st[mi][ni][r] = p;
                        ls += p;
                    }
                ls += __shfl_xor(ls, 16, 64);
                ls += __shfl_xor(ls, 32, 64);
                lrun[ni] = lrun[ni] * fac[ni] + ls;
            }
            if (quad == 0)
#pragma unroll
                for (int ni = 0; ni < 4; ++ni) sc[wave][ni * 16 + l16] = fac[ni];
#pragma unroll
            for (int mi = 0; mi < 4; ++mi) {
                const f32x4 f4 = *(const f32x4*)&sc[wave][mi * 16 + quad * 4];
#pragma unroll
                for (int ni = 0; ni < 4; ++ni)
#pragma unroll
                    for (int r = 0; r < 4; ++r) acc[mi][ni][r] *= f4[r];
            }
            char* Pb = (char*)Pl + wave * 8192;
#pragma unroll
            for (int ni = 0; ni < 4; ++ni) {
                const int qrow = ni * 16 + l16;
#pragma unroll
                for (int mi = 0; mi < 4; ++mi) {
                    union { bf16 bv[4]; uint2 u2; } pk;
#pragma unroll
                    for (int r = 0; r < 4; ++r)
                        pk.bv[r] = __float2bfloat16(st[mi][ni][r]);
                    *(uint2*)(Pb + swzb(qrow, mi * 32 + quad * 8)) = pk.u2;
                }
            }
            // O += P @ V
#pragma unroll
            for (int kc = 0; kc < 2; ++kc) {
                bf16x8 pf[4], vf[4];
#pragma unroll
                for (int mi = 0; mi < 4; ++mi)
                    pf[mi] = *(const bf16x8*)(Pb +
                             swzb(mi * 16 + l16, kc * 64 + quad * 16));
#pragma unroll
                for (int ni = 0; ni < 4; ++ni)
                    vf[ni] = *(const bf16x8*)((char*)Vt +
                             swzb(ni * 16 + l16, kc * 64 + quad * 16));
#pragma unroll
                for (int mi = 0; mi < 4; ++mi)
#pragma unroll
                    for (int ni = 0; ni < 4; ++ni)
                        acc[mi][ni] = __builtin_amdgcn_mfma_f32_16x16x32_bf16(
                            pf[mi], vf[ni], acc[mi][ni], 0, 0, 0);
            }
        }
    }
    if (quad == 0)
#pragma unroll
        for (int ni = 0; ni < 4; ++ni) sc[wave][ni * 16 + l16] = lrun[ni];
#pragma unroll
    for (int mi = 0; mi < 4; ++mi) {
        const f32x4 l4 = *(const f32x4*)&sc[wave][mi * 16 + quad * 4];
#pragma unroll
        for (int r = 0; r < 4; ++r) {
            const float inv = 1.f / l4[r];
            const int row = q0w + mi * 16 + quad * 4 + r;
            bf16* orow = o + ((size_t)b * 1024 + row) * 1024 + h * 64;
#pragma unroll
            for (int ni = 0; ni < 4; ++ni)
                orow[ni * 16 + l16] = __float2bfloat16(acc[mi][ni][r] * inv);
        }
    }
}

// ---------------------------------------------------------------- launch
extern "C" void kernel_launch(void* const* d_in, const int* in_sizes, int n_in,
                              void* d_out, int out_size, void* d_ws, size_t ws_size,
                              hipStream_t stream) {
    (void)out_size; (void)ws_size;
    const float* x = (const float*)d_in[0];
    const int base = (n_in >= 18 && in_sizes[1] > 4096) ? 2 : 1;  // skip mask
    const float* ln1s = (const float*)d_in[base + 0];
    const float* ln1b = (const float*)d_in[base + 1];
    const float* wq   = (const float*)d_in[base + 2];
    const float* bq   = (const float*)d_in[base + 3];
    const float* wk   = (const float*)d_in[base + 4];
    const float* bk   = (const float*)d_in[base + 5];
    const float* wv   = (const float*)d_in[base + 6];
    const float* bv   = (const float*)d_in[base + 7];
    const float* wo   = (const float*)d_in[base + 8];
    const float* bo   = (const float*)d_in[base + 9];
    const float* ln2s = (const float*)d_in[base + 10];
    const float* ln2b = (const float*)d_in[base + 11];
    const float* w1   = (const float*)d_in[base + 12];
    const float* b1   = (const float*)d_in[base + 13];
    const float* w2   = (const float*)d_in[base + 14];
    const float* b2   = (const float*)d_in[base + 15];
    float* out = (float*)d_out;   // fp32 output (also used as scratch)

    // Workspace map (64MB), phase-disjoint lifetimes:
    //   ws[0,16)  h (LN1) -> ao (attn out) -> h2 (LN2 out)
    //   ws[16,64) qkv [8192][3072] bf16 -> woT[16,18) -> f1c[16,48)
    //   ws[48,56) w1T  (after attn)      ws[56,64) w2T
    // d_out (32MB fp32) as scratch early:
    //   out[0,6MB) wqkvT bf16 [3072][1024]; out[8MB) bqkv [3072] fp32
    //   -> x2 fp32 (wo GEMM, residual) -> final output (FFN2 ACC)
    char* ws = (char*)d_ws;
    char* oc = (char*)d_out;
    const size_t MB = 1ull << 20;
    bf16* h     = (bf16*)(ws + 0 * MB);
    bf16* qkv   = (bf16*)(ws + 16 * MB);
    bf16* ao    = (bf16*)(ws + 0 * MB);
    bf16* h2    = (bf16*)(ws + 0 * MB);
    bf16* woT   = (bf16*)(ws + 16 * MB);
    bf16* f1c   = (bf16*)(ws + 16 * MB);   // [8192][2048] bf16, 32MB
    bf16* w1T   = (bf16*)(ws + 48 * MB);
    bf16* w2T   = (bf16*)(ws + 56 * MB);
    bf16* wqkvT = (bf16*)(oc + 0 * MB);
    float* bqkv = (float*)(oc + 8 * MB);

    const dim3 tb(256);

    layernorm_k<float><<<8192, tb, 0, stream>>>(x, ln1s, ln1b, h);
    transpose_k<<<dim3(32, 32), tb, 0, stream>>>(wq, wqkvT, 1024, 1024);
    transpose_k<<<dim3(32, 32), tb, 0, stream>>>(wk, wqkvT + 1024 * 1024, 1024, 1024);
    transpose_k<<<dim3(32, 32), tb, 0, stream>>>(wv, wqkvT + 2 * 1024 * 1024, 1024, 1024);
    catb_k<<<12, tb, 0, stream>>>(bq, bk, bv, bqkv);
    // fused QKV: [8192][3072] = h @ wqkvT
    mgemm_k<0, 0, 0, float, bf16><<<dim3(24, 64), tb, 0, stream>>>(
        h, wqkvT, 1024, bqkv, nullptr, qkv, 8192, 3072, 1024);
    attn_k<<<dim3(4, 16, 8), tb, 0, stream>>>(qkv, qkv + 1024, qkv + 2048, ao, 3072);
    // qkv dead: transpose remaining weights
    transpose_k<<<dim3(32, 32), tb, 0, stream>>>(wo, woT, 1024, 1024);
    transpose_k<<<dim3(128, 32), tb, 0, stream>>>(w1, w1T, 1024, 4096);
    transpose_k<<<dim3(32, 128), tb, 0, stream>>>(w2, w2T, 4096, 1024);
    // x2 = ao @ woT + bo + x  -> fp32 directly into out (residual stream)
    mgemm_k<0, 1, 0, float, float><<<dim3(8, 64), tb, 0, stream>>>(
        ao, woT, 1024, bo, x, out, 8192, 1024, 1024);
    layernorm_k<float><<<8192, tb, 0, stream>>>(out, ln2s, ln2b, h2);
    // FFN in 2 chunks of 2048; FFN2 accumulates onto out (holds x2)
    for (int c = 0; c < 2; ++c) {
        mgemm_k<1, 0, 0, float, bf16><<<dim3(16, 64), tb, 0, stream>>>(
            h2, w1T + (size_t)c * 2048 * 1024, 1024, b1 + c * 2048, nullptr,
            f1c, 8192, 2048, 1024);
        mgemm_k<0, 0, 1, float, float><<<dim3(8, 64), tb, 0, stream>>>(
            f1c, w2T + c * 2048, 4096, c ? nullptr : b2, nullptr,
            out, 8192, 1024, 2048);
    }
}

// Round 3
// 641.966 us; speedup vs baseline: 2.8554x; 1.0880x over previous
//
#include <hip/hip_runtime.h>
#include <hip/hip_bf16.h>

using bf16 = __hip_bfloat16;
typedef __attribute__((ext_vector_type(8))) short bf16x8;   // 8 bf16 = 4 VGPRs
typedef __attribute__((ext_vector_type(4))) float f32x4;

__device__ inline float u2f(unsigned int u) { return __uint_as_float(u << 16); }
__device__ inline float toF(float x) { return x; }
__device__ inline float toF(bf16 x) { return __bfloat162float(x); }
__device__ inline void storeO(float* p, float v) { *p = v; }
__device__ inline void storeO(bf16* p, float v) { *p = __float2bfloat16(v); }

// async global->LDS, 16B per lane. LDS dest must be wave-uniform base
// (HW adds lane*16); global src is per-lane.
__device__ inline void gload_lds16(const void* g, void* l) {
    __builtin_amdgcn_global_load_lds(
        (const __attribute__((address_space(1))) void*)g,
        (__attribute__((address_space(3))) void*)l, 16, 0, 0);
}

// workgroup barrier that does NOT drain vmcnt (prefetch loads stay in
// flight). lgkmcnt(0) orders this wave's LDS ops; raw s_barrier syncs.
// Pattern verified in the m201 8-phase template.
__device__ inline void wgbar() {
    asm volatile("s_waitcnt lgkmcnt(0)" ::: "memory");
    __builtin_amdgcn_s_barrier();
    asm volatile("" ::: "memory");
}

// byte offset into a [64][128B] LDS tile with XOR swizzle (attn tiles)
__device__ inline int swzb(int row, int bcol) {
    return row * 128 + (bcol ^ (((row ^ (row >> 3)) & 7) << 4));
}

// ---------------------------------------------------------------- transpose
// fp32 [R,C] -> bf16 [C,R]. R, C multiples of 32. block = 256 (32x8 logical).
__global__ __launch_bounds__(256) void transpose_k(const float* __restrict__ in,
                                                   bf16* __restrict__ out,
                                                   int R, int C) {
    __shared__ float tile[32][33];
    const int c0 = blockIdx.x * 32, r0 = blockIdx.y * 32;
    const int tx = threadIdx.x & 31, ty = threadIdx.x >> 5;
#pragma unroll
    for (int i = 0; i < 32; i += 8)
        tile[ty + i][tx] = in[(size_t)(r0 + ty + i) * C + (c0 + tx)];
    __syncthreads();
#pragma unroll
    for (int i = 0; i < 32; i += 8)
        out[(size_t)(c0 + ty + i) * R + (r0 + tx)] = __float2bfloat16(tile[tx][ty + i]);
}

// concat 3x1024 fp32 biases -> [3072]
__global__ __launch_bounds__(256) void catb_k(const float* __restrict__ a,
                                              const float* __restrict__ b,
                                              const float* __restrict__ c,
                                              float* __restrict__ o) {
    const int t = blockIdx.x * 256 + threadIdx.x;
    const float* s = t < 1024 ? a : (t < 2048 ? b : c);
    o[t] = s[t & 1023];
}

// ---------------------------------------------------------------- layernorm
__device__ inline float waveRedSum(float x) {
#pragma unroll
    for (int off = 32; off; off >>= 1) x += __shfl_xor(x, off, 64);
    return x;
}

template <typename T>
__global__ __launch_bounds__(256) void layernorm_k(const T* __restrict__ in,
                                                   const float* __restrict__ g,
                                                   const float* __restrict__ bta,
                                                   bf16* __restrict__ out) {
    const int row = blockIdx.x, t = threadIdx.x;
    const int lane = t & 63, wid = t >> 6;
    const T* xr = in + (size_t)row * 1024;
    float v0, v1, v2, v3;
    if constexpr (sizeof(T) == 4) {
        float4 u = ((const float4*)xr)[t];
        v0 = u.x; v1 = u.y; v2 = u.z; v3 = u.w;
    } else {
        ushort4 u = ((const ushort4*)xr)[t];
        v0 = u2f(u.x); v1 = u2f(u.y); v2 = u2f(u.z); v3 = u2f(u.w);
    }
    __shared__ float red[8];
    float s = waveRedSum(v0 + v1 + v2 + v3);
    if (lane == 0) red[wid] = s;
    __syncthreads();
    float mu = (red[0] + red[1] + red[2] + red[3]) * (1.f / 1024.f);
    float d0 = v0 - mu, d1 = v1 - mu, d2 = v2 - mu, d3 = v3 - mu;
    float ss = waveRedSum(d0 * d0 + d1 * d1 + d2 * d2 + d3 * d3);
    if (lane == 0) red[4 + wid] = ss;
    __syncthreads();
    float var = (red[4] + red[5] + red[6] + red[7]) * (1.f / 1024.f);
    float inv = rsqrtf(var + 1e-6f);
    const int c = t * 4;
    bf16* orow = out + (size_t)row * 1024;
    orow[c + 0] = __float2bfloat16(d0 * inv * g[c + 0] + bta[c + 0]);
    orow[c + 1] = __float2bfloat16(d1 * inv * g[c + 1] + bta[c + 1]);
    orow[c + 2] = __float2bfloat16(d2 * inv * g[c + 2] + bta[c + 2]);
    orow[c + 3] = __float2bfloat16(d3 * inv * g[c + 3] + bta[c + 3]);
}

// ---------------------------------------------------------------- MFMA GEMM
// C[M,N] = A[M,K](bf16,[M][K]) @ B(bf16,[N][K] row-stride ldB) + bias.
// 128x128 tile/block, 256 thr = 2x2 waves of 64x64 (4x4 mfma 16x16x32).
// 2-phase double-buffered pipeline (T3-min): issue next K-step's
// global_load_lds AFTER the barrier, compute current buffer while loads
// fly, one __syncthreads per K-step drains them after compute.
// Staging swizzle: LDS linear in slot; k-chunk XOR-permuted at the GLOBAL
// source; fragment reads apply the same XOR (both-sides, rule #21).
template <int GELU, int RES, int ACC, typename RT, typename OT>
__global__ __launch_bounds__(256) void mgemm_k(const bf16* __restrict__ A,
                                               const bf16* __restrict__ B, int ldB,
                                               const float* __restrict__ bias,
                                               const RT* __restrict__ resid,
                                               OT* C, int M, int N, int K) {
    __shared__ bf16 As[2 * 128 * 32];
    __shared__ bf16 Bs[2 * 128 * 32];
    const int tid = threadIdx.x;
    const int lane = tid & 63, wid = tid >> 6;
    const int l16 = lane & 15, quad = lane >> 4;
    const int wm = (wid >> 1) * 64, wn = (wid & 1) * 64;
    const int m0 = blockIdx.y * 128, n0 = blockIdx.x * 128;

    const int r0 = tid >> 2, sc0 = tid & 3;
    const int lc0 = sc0 ^ ((r0 >> 1) & 3);
    const int r1 = r0 + 64;
    const int lc1 = sc0 ^ ((r1 >> 1) & 3);
    const bf16* gA0 = A + (size_t)(m0 + r0) * K + lc0 * 8;
    const bf16* gA1 = A + (size_t)(m0 + r1) * K + lc1 * 8;
    const bf16* gB0 = B + (size_t)(n0 + r0) * ldB + lc0 * 8;
    const bf16* gB1 = B + (size_t)(n0 + r1) * ldB + lc1 * 8;
    char* asb = (char*)As;
    char* bsb = (char*)Bs;
    const int lb0 = wid * 1024, lb1 = 4096 + wid * 1024;  // wave-uniform bases
    const int rdsw = (quad ^ ((l16 >> 1) & 3)) * 16;      // frag-read swizzle

    f32x4 acc[4][4] = {};
    const int nT = K >> 5;
    // prologue: stage tile 0 into buf 0
    gload_lds16(gA0, asb + lb0);
    gload_lds16(gA1, asb + lb1);
    gload_lds16(gB0, bsb + lb0);
    gload_lds16(gB1, bsb + lb1);
    __syncthreads();
    for (int t = 0; t < nT; ++t) {
        const int cur = t & 1;
        if (t + 1 < nT) {   // prefetch next K-step into other buffer
            char* ab = asb + (cur ^ 1) * 8192;
            char* bb = bsb + (cur ^ 1) * 8192;
            const int ko = (t + 1) * 32;
            gload_lds16(gA0 + ko, ab + lb0);
            gload_lds16(gA1 + ko, ab + lb1);
            gload_lds16(gB0 + ko, bb + lb0);
            gload_lds16(gB1 + ko, bb + lb1);
        }
        const char* ar = asb + cur * 8192;
        const char* br = bsb + cur * 8192;
        bf16x8 a[4], b[4];
#pragma unroll
        for (int i = 0; i < 4; ++i)
            a[i] = *(const bf16x8*)(ar + (wm + i * 16 + l16) * 64 + rdsw);
#pragma unroll
        for (int i = 0; i < 4; ++i)
            b[i] = *(const bf16x8*)(br + (wn + i * 16 + l16) * 64 + rdsw);
#pragma unroll
        for (int mi = 0; mi < 4; ++mi)
#pragma unroll
            for (int ni = 0; ni < 4; ++ni)
                acc[mi][ni] = __builtin_amdgcn_mfma_f32_16x16x32_bf16(
                    a[mi], b[ni], acc[mi][ni], 0, 0, 0);
        __syncthreads();   // drains prefetch (flew during compute) + lgkm
    }
#pragma unroll
    for (int mi = 0; mi < 4; ++mi) {
#pragma unroll
        for (int ni = 0; ni < 4; ++ni) {
            const int col = n0 + wn + ni * 16 + l16;
            const float bv = bias ? bias[col] : 0.f;
#pragma unroll
            for (int r = 0; r < 4; ++r) {
                const int row = m0 + wm + mi * 16 + quad * 4 + r;
                float val = acc[mi][ni][r] + bv;
                if (GELU) {
                    float z = 0.7978845608028654f * (val + 0.044715f * val * val * val);
                    float th = 1.f - 2.f / (__expf(2.f * z) + 1.f);
                    val = 0.5f * val * (1.f + th);
                }
                const size_t idx = (size_t)row * N + col;
                if (RES) val += toF(resid[idx]);
                if (ACC) val += toF(C[idx]);
                storeO(&C[idx], val);
            }
        }
    }
}

// ---------------------------------------------------------------- attention
// MFMA flash attention with register-staged K/V prefetch (T14).
// q,k,v: [8,1024,16,64] bf16 views with row stride rs (qkv packed
// [8192][3072] -> rs=3072); o: [8,1024,16,64] (stride 1024).
// Block = 256 thr = 4 waves; each wave owns 64 q-rows x D=64 output.
// Per tile: wgbar -> LDS-write prev-loaded regs -> issue next tile's global
// loads (fly across the compute phase; wgbar does NOT drain vmcnt) ->
// wgbar -> MFMA S^T / softmax / P / PV.
__global__ __launch_bounds__(256) void attn_k(const bf16* __restrict__ q,
                                              const bf16* __restrict__ k,
                                              const bf16* __restrict__ v,
                                              bf16* __restrict__ o, int rs) {
    const int b = blockIdx.z, h = blockIdx.y;
    const int qi = 3 - blockIdx.x;            // longest blocks dispatch first
    const int qblock = qi * 256;
    const int tid = threadIdx.x;
    const int wave = tid >> 6, lane = tid & 63;
    const int l16 = lane & 15, quad = lane >> 4;
    const int q0w = qblock + wave * 64;

    __shared__ __align__(16) bf16 Kl[64 * 64];       // [k][d] swizzled
    __shared__ __align__(16) bf16 Vt[64 * 64];       // [d][k] swizzled
    __shared__ __align__(16) bf16 Pl[4 * 64 * 64];   // per-wave [q][k] swizzled
    __shared__ __align__(16) float sc[4][64];        // per-wave per-q scratch

    bf16x8 qf[4][2];
#pragma unroll
    for (int ni = 0; ni < 4; ++ni) {
        const int row = q0w + ni * 16 + l16;
        const bf16* qp = q + ((size_t)b * 1024 + row) * rs + h * 64;
#pragma unroll
        for (int kc = 0; kc < 2; ++kc)
            qf[ni][kc] = *(const bf16x8*)(qp + kc * 32 + quad * 8);
    }

    f32x4 acc[4][4] = {};     // O: row q = mi*16+quad*4+r, col d = ni*16+l16
    float mrun[4], lrun[4];
#pragma unroll
    for (int ni = 0; ni < 4; ++ni) { mrun[ni] = -1e30f; lrun[ni] = 0.f; }

    const int NT = qi * 4 + 4;
    const int myNT = qi * 4 + wave + 1;

    // staging geometry (per thread)
    const int kr_ = tid >> 3, kch = tid & 7;          // K: rows kr_, kr_+32
    const int vr_ = (tid >> 3) * 2, vdb = (tid & 7) * 8;  // V: rows vr_, vr_+1
    uint4 kA, kB, vA, vB;
    {   // prefetch tile 0
        const size_t gk = ((size_t)b * 1024 + 0 + kr_) * rs + h * 64 + kch * 8;
        kA = *(const uint4*)(k + gk);
        kB = *(const uint4*)(k + gk + (size_t)32 * rs);
        const size_t gv = ((size_t)b * 1024 + 0 + vr_) * rs + h * 64 + vdb;
        vA = *(const uint4*)(v + gv);
        vB = *(const uint4*)(v + gv + rs);
    }

    for (int t = 0; t < NT; ++t) {
        wgbar();   // all waves done reading Kl/Vt from previous tile
        // ---- write prefetched K (row-major, swizzled) ----
        *(uint4*)((char*)Kl + swzb(kr_, kch * 16)) = kA;
        *(uint4*)((char*)Kl + swzb(kr_ + 32, kch * 16)) = kB;
        // ---- write prefetched V transposed (Vt[d][k], swizzled) ----
        {
            const unsigned aw[4] = {vA.x, vA.y, vA.z, vA.w};
            const unsigned bw[4] = {vB.x, vB.y, vB.z, vB.w};
#pragma unroll
            for (int j = 0; j < 8; ++j) {
                const unsigned lo = (aw[j >> 1] >> ((j & 1) * 16)) & 0xffffu;
                const unsigned hi = (bw[j >> 1] >> ((j & 1) * 16)) & 0xffffu;
                *(unsigned*)((char*)Vt + swzb(vdb + j, vr_ * 2)) = lo | (hi << 16);
            }
        }
        // ---- issue next tile's global loads (fly across compute) ----
        if (t + 1 < NT) {
            const int j1 = (t + 1) * 64;
            const size_t gk = ((size_t)b * 1024 + j1 + kr_) * rs + h * 64 + kch * 8;
            kA = *(const uint4*)(k + gk);
            kB = *(const uint4*)(k + gk + (size_t)32 * rs);
            const size_t gv = ((size_t)b * 1024 + j1 + vr_) * rs + h * 64 + vdb;
            vA = *(const uint4*)(v + gv);
            vB = *(const uint4*)(v + gv + rs);
        }
        wgbar();   // staged tile visible to all waves
        if (t < myNT) {
            const int j0 = t * 64;
            // S^T = K @ Q^T
            f32x4 st[4][4] = {};
#pragma unroll
            for (int kc = 0; kc < 2; ++kc) {
                bf16x8 kf[4];
#pragma unroll
                for (int mi = 0; mi < 4; ++mi)
                    kf[mi] = *(const bf16x8*)((char*)Kl +
                             swzb(mi * 16 + l16, kc * 64 + quad * 16));
#pragma unroll
                for (int mi = 0; mi < 4; ++mi)
#pragma unroll
                    for (int ni = 0; ni < 4; ++ni)
                        st[mi][ni] = __builtin_amdgcn_mfma_f32_16x16x32_bf16(
                            kf[mi], qf[ni][kc], st[mi][ni], 0, 0, 0);
            }
            if (j0 == q0w) {  // causal mask, diagonal tile only
#pragma unroll
                for (int mi = 0; mi < 4; ++mi)
#pragma unroll
                    for (int ni = 0; ni < 4; ++ni)
#pragma unroll
                        for (int r = 0; r < 4; ++r)
                            if (mi * 16 + quad * 4 + r > ni * 16 + l16)
                                st[mi][ni][r] = -1e30f;
            }
            // online softmax (1/8 scale folded into exp)
            float fac[4];
#pragma unroll
            for (int ni = 0; ni < 4; ++ni) {
                float mx = -1e30f;
#pragma unroll
                for (int mi = 0; mi < 4; ++mi)
#pragma unroll
                    for (int r = 0; r < 4; ++r) mx = fmaxf(mx, st[mi][ni][r]);
                mx = fmaxf(mx, __shfl_xor(mx, 16, 64));
                mx = fmaxf(mx, __shfl_xor(mx, 32, 64));
                const float nm = fmaxf(mrun[ni], mx);
                fac[ni] = __expf((mrun[ni] - nm) * 0.125f);
                mrun[ni] = nm;
                float ls = 0.f;
#pragma unroll
                for (int mi = 0; mi < 4; ++mi)
#pragma unroll
                    for (int r = 0; r < 4; ++r) {
                        const float p = __expf((st[mi][ni][r] - nm) * 0.125f);
                        st[mi][ni][r] = p;
                        ls += p;
                    }
                ls += __shfl_xor(ls, 16, 64);
                ls += __shfl_xor(ls, 32, 64);
                lrun[ni] = lrun[ni] * fac[ni] + ls;
            }
            if (quad == 0)
#pragma unroll
                for (int ni = 0; ni < 4; ++ni) sc[wave][ni * 16 + l16] = fac[ni];
#pragma unroll
            for (int mi = 0; mi < 4; ++mi) {
                const f32x4 f4 = *(const f32x4*)&sc[wave][mi * 16 + quad * 4];
#pragma unroll
                for (int ni = 0; ni < 4; ++ni)
#pragma unroll
                    for (int r = 0; r < 4; ++r) acc[mi][ni][r] *= f4[r];
            }
            char* Pb = (char*)Pl + wave * 8192;
#pragma unroll
            for (int ni = 0; ni < 4; ++ni) {
                const int qrow = ni * 16 + l16;
#pragma unroll
                for (int mi = 0; mi < 4; ++mi) {
                    union { bf16 bv[4]; uint2 u2; } pk;
#pragma unroll
                    for (int r = 0; r < 4; ++r)
                        pk.bv[r] = __float2bfloat16(st[mi][ni][r]);
                    *(uint2*)(Pb + swzb(qrow, mi * 32 + quad * 8)) = pk.u2;
                }
            }
            // O += P @ V
#pragma unroll
            for (int kc = 0; kc < 2; ++kc) {
                bf16x8 pf[4], vf[4];
#pragma unroll
                for (int mi = 0; mi < 4; ++mi)
                    pf[mi] = *(const bf16x8*)(Pb +
                             swzb(mi * 16 + l16, kc * 64 + quad * 16));
#pragma unroll
                for (int ni = 0; ni < 4; ++ni)
                    vf[ni] = *(const bf16x8*)((char*)Vt +
                             swzb(ni * 16 + l16, kc * 64 + quad * 16));
#pragma unroll
                for (int mi = 0; mi < 4; ++mi)
#pragma unroll
                    for (int ni = 0; ni < 4; ++ni)
                        acc[mi][ni] = __builtin_amdgcn_mfma_f32_16x16x32_bf16(
                            pf[mi], vf[ni], acc[mi][ni], 0, 0, 0);
            }
        }
    }
    if (quad == 0)
#pragma unroll
        for (int ni = 0; ni < 4; ++ni) sc[wave][ni * 16 + l16] = lrun[ni];
#pragma unroll
    for (int mi = 0; mi < 4; ++mi) {
        const f32x4 l4 = *(const f32x4*)&sc[wave][mi * 16 + quad * 4];
#pragma unroll
        for (int r = 0; r < 4; ++r) {
            const float inv = 1.f / l4[r];
            const int row = q0w + mi * 16 + quad * 4 + r;
            bf16* orow = o + ((size_t)b * 1024 + row) * 1024 + h * 64;
#pragma unroll
            for (int ni = 0; ni < 4; ++ni)
                orow[ni * 16 + l16] = __float2bfloat16(acc[mi][ni][r] * inv);
        }
    }
}

// ---------------------------------------------------------------- launch
extern "C" void kernel_launch(void* const* d_in, const int* in_sizes, int n_in,
                              void* d_out, int out_size, void* d_ws, size_t ws_size,
                              hipStream_t stream) {
    (void)out_size; (void)ws_size;
    const float* x = (const float*)d_in[0];
    const int base = (n_in >= 18 && in_sizes[1] > 4096) ? 2 : 1;  // skip mask
    const float* ln1s = (const float*)d_in[base + 0];
    const float* ln1b = (const float*)d_in[base + 1];
    const float* wq   = (const float*)d_in[base + 2];
    const float* bq   = (const float*)d_in[base + 3];
    const float* wk   = (const float*)d_in[base + 4];
    const float* bk   = (const float*)d_in[base + 5];
    const float* wv   = (const float*)d_in[base + 6];
    const float* bv   = (const float*)d_in[base + 7];
    const float* wo   = (const float*)d_in[base + 8];
    const float* bo   = (const float*)d_in[base + 9];
    const float* ln2s = (const float*)d_in[base + 10];
    const float* ln2b = (const float*)d_in[base + 11];
    const float* w1   = (const float*)d_in[base + 12];
    const float* b1   = (const float*)d_in[base + 13];
    const float* w2   = (const float*)d_in[base + 14];
    const float* b2   = (const float*)d_in[base + 15];
    float* out = (float*)d_out;   // fp32 output (also used as scratch)

    // Workspace map (64MB), phase-disjoint lifetimes:
    //   ws[0,16)  h (LN1) -> ao (attn out) -> h2 (LN2 out)
    //   ws[16,64) qkv [8192][3072] bf16 -> woT[16,18) -> f1c[16,48)
    //   ws[48,56) w1T  (after attn)      ws[56,64) w2T
    // d_out (32MB fp32) as scratch early:
    //   out[0,6MB) wqkvT bf16 [3072][1024]; out[8MB) bqkv [3072] fp32
    //   -> x2 fp32 (wo GEMM, residual) -> final output (FFN2 ACC)
    char* ws = (char*)d_ws;
    char* oc = (char*)d_out;
    const size_t MB = 1ull << 20;
    bf16* h     = (bf16*)(ws + 0 * MB);
    bf16* qkv   = (bf16*)(ws + 16 * MB);
    bf16* ao    = (bf16*)(ws + 0 * MB);
    bf16* h2    = (bf16*)(ws + 0 * MB);
    bf16* woT   = (bf16*)(ws + 16 * MB);
    bf16* f1c   = (bf16*)(ws + 16 * MB);   // [8192][2048] bf16, 32MB
    bf16* w1T   = (bf16*)(ws + 48 * MB);
    bf16* w2T   = (bf16*)(ws + 56 * MB);
    bf16* wqkvT = (bf16*)(oc + 0 * MB);
    float* bqkv = (float*)(oc + 8 * MB);

    const dim3 tb(256);

    layernorm_k<float><<<8192, tb, 0, stream>>>(x, ln1s, ln1b, h);
    transpose_k<<<dim3(32, 32), tb, 0, stream>>>(wq, wqkvT, 1024, 1024);
    transpose_k<<<dim3(32, 32), tb, 0, stream>>>(wk, wqkvT + 1024 * 1024, 1024, 1024);
    transpose_k<<<dim3(32, 32), tb, 0, stream>>>(wv, wqkvT + 2 * 1024 * 1024, 1024, 1024);
    catb_k<<<12, tb, 0, stream>>>(bq, bk, bv, bqkv);
    // fused QKV: [8192][3072] = h @ wqkvT
    mgemm_k<0, 0, 0, float, bf16><<<dim3(24, 64), tb, 0, stream>>>(
        h, wqkvT, 1024, bqkv, nullptr, qkv, 8192, 3072, 1024);
    attn_k<<<dim3(4, 16, 8), tb, 0, stream>>>(qkv, qkv + 1024, qkv + 2048, ao, 3072);
    // qkv dead: transpose remaining weights
    transpose_k<<<dim3(32, 32), tb, 0, stream>>>(wo, woT, 1024, 1024);
    transpose_k<<<dim3(128, 32), tb, 0, stream>>>(w1, w1T, 1024, 4096);
    transpose_k<<<dim3(32, 128), tb, 0, stream>>>(w2, w2T, 4096, 1024);
    // x2 = ao @ woT + bo + x  -> fp32 directly into out (residual stream)
    mgemm_k<0, 1, 0, float, float><<<dim3(8, 64), tb, 0, stream>>>(
        ao, woT, 1024, bo, x, out, 8192, 1024, 1024);
    layernorm_k<float><<<8192, tb, 0, stream>>>(out, ln2s, ln2b, h2);
    // FFN in 2 chunks of 2048; FFN2 accumulates onto out (holds x2)
    for (int c = 0; c < 2; ++c) {
        mgemm_k<1, 0, 0, float, bf16><<<dim3(16, 64), tb, 0, stream>>>(
            h2, w1T + (size_t)c * 2048 * 1024, 1024, b1 + c * 2048, nullptr,
            f1c, 8192, 2048, 1024);
        mgemm_k<0, 0, 1, float, float><<<dim3(8, 64), tb, 0, stream>>>(
            f1c, w2T + c * 2048, 4096, c ? nullptr : b2, nullptr,
            out, 8192, 1024, 2048);
    }
}

// Round 4
// 584.349 us; speedup vs baseline: 3.1370x; 1.0986x over previous
//
#include <hip/hip_runtime.h>
#include <hip/hip_bf16.h>

using bf16 = __hip_bfloat16;
typedef __attribute__((ext_vector_type(8))) short bf16x8;   // 8 bf16 = 4 VGPRs
typedef __attribute__((ext_vector_type(4))) float f32x4;

__device__ inline float u2f(unsigned int u) { return __uint_as_float(u << 16); }
__device__ inline float toF(float x) { return x; }
__device__ inline float toF(bf16 x) { return __bfloat162float(x); }
__device__ inline void storeO(float* p, float v) { *p = v; }
__device__ inline void storeO(bf16* p, float v) { *p = __float2bfloat16(v); }

// async global->LDS, 16B per lane. LDS dest must be wave-uniform base
// (HW adds lane*16); global src is per-lane.
__device__ inline void gload_lds16(const void* g, void* l) {
    __builtin_amdgcn_global_load_lds(
        (const __attribute__((address_space(1))) void*)g,
        (__attribute__((address_space(3))) void*)l, 16, 0, 0);
}

// workgroup barrier that does NOT drain vmcnt (prefetch loads stay in
// flight). lgkmcnt(0) orders this wave's LDS ops; raw s_barrier syncs.
__device__ inline void wgbar() {
    asm volatile("s_waitcnt lgkmcnt(0)" ::: "memory");
    __builtin_amdgcn_s_barrier();
    asm volatile("" ::: "memory");
}

// byte offset into a [64][128B] LDS tile with XOR swizzle (bank-conflict fix)
__device__ inline int swzb(int row, int bcol) {
    return row * 128 + (bcol ^ (((row ^ (row >> 3)) & 7) << 4));
}

// ---------------------------------------------------------------- transpose
// fp32 [R,C] -> bf16 [C,R]. R, C multiples of 32. block = 256 (32x8 logical).
__global__ __launch_bounds__(256) void transpose_k(const float* __restrict__ in,
                                                   bf16* __restrict__ out,
                                                   int R, int C) {
    __shared__ float tile[32][33];
    const int c0 = blockIdx.x * 32, r0 = blockIdx.y * 32;
    const int tx = threadIdx.x & 31, ty = threadIdx.x >> 5;
#pragma unroll
    for (int i = 0; i < 32; i += 8)
        tile[ty + i][tx] = in[(size_t)(r0 + ty + i) * C + (c0 + tx)];
    __syncthreads();
#pragma unroll
    for (int i = 0; i < 32; i += 8)
        out[(size_t)(c0 + ty + i) * R + (r0 + tx)] = __float2bfloat16(tile[tx][ty + i]);
}

// concat 3x1024 fp32 biases -> [3072]
__global__ __launch_bounds__(256) void catb_k(const float* __restrict__ a,
                                              const float* __restrict__ b,
                                              const float* __restrict__ c,
                                              float* __restrict__ o) {
    const int t = blockIdx.x * 256 + threadIdx.x;
    const float* s = t < 1024 ? a : (t < 2048 ? b : c);
    o[t] = s[t & 1023];
}

// ---------------------------------------------------------------- layernorm
__device__ inline float waveRedSum(float x) {
#pragma unroll
    for (int off = 32; off; off >>= 1) x += __shfl_xor(x, off, 64);
    return x;
}

template <typename T>
__global__ __launch_bounds__(256) void layernorm_k(const T* __restrict__ in,
                                                   const float* __restrict__ g,
                                                   const float* __restrict__ bta,
                                                   bf16* __restrict__ out) {
    const int row = blockIdx.x, t = threadIdx.x;
    const int lane = t & 63, wid = t >> 6;
    const T* xr = in + (size_t)row * 1024;
    float v0, v1, v2, v3;
    if constexpr (sizeof(T) == 4) {
        float4 u = ((const float4*)xr)[t];
        v0 = u.x; v1 = u.y; v2 = u.z; v3 = u.w;
    } else {
        ushort4 u = ((const ushort4*)xr)[t];
        v0 = u2f(u.x); v1 = u2f(u.y); v2 = u2f(u.z); v3 = u2f(u.w);
    }
    __shared__ float red[8];
    float s = waveRedSum(v0 + v1 + v2 + v3);
    if (lane == 0) red[wid] = s;
    __syncthreads();
    float mu = (red[0] + red[1] + red[2] + red[3]) * (1.f / 1024.f);
    float d0 = v0 - mu, d1 = v1 - mu, d2 = v2 - mu, d3 = v3 - mu;
    float ss = waveRedSum(d0 * d0 + d1 * d1 + d2 * d2 + d3 * d3);
    if (lane == 0) red[4 + wid] = ss;
    __syncthreads();
    float var = (red[4] + red[5] + red[6] + red[7]) * (1.f / 1024.f);
    float inv = rsqrtf(var + 1e-6f);
    const int c = t * 4;
    bf16* orow = out + (size_t)row * 1024;
    orow[c + 0] = __float2bfloat16(d0 * inv * g[c + 0] + bta[c + 0]);
    orow[c + 1] = __float2bfloat16(d1 * inv * g[c + 1] + bta[c + 1]);
    orow[c + 2] = __float2bfloat16(d2 * inv * g[c + 2] + bta[c + 2]);
    orow[c + 3] = __float2bfloat16(d3 * inv * g[c + 3] + bta[c + 3]);
}

// ---------------------------------------------------------------- MFMA GEMM
// C[M,N] = A[M,K](bf16,[M][K]) @ B(bf16,[N][K] row-stride ldB) + bias.
// 128x128 tile/block, 256 thr = 2x2 waves of 64x64 (4x4 mfma 16x16x32).
// 2-phase double-buffered pipeline (T3-min). 1-D grid with bijective
// XCD-aware swizzle (T1): XCD x gets a contiguous chunk of output tiles
// (requires gridDim.x % 8 == 0 -- true for all call sites).
template <int GELU, int RES, int ACC, typename RT, typename OT>
__global__ __launch_bounds__(256) void mgemm_k(const bf16* __restrict__ A,
                                               const bf16* __restrict__ B, int ldB,
                                               const float* __restrict__ bias,
                                               const RT* __restrict__ resid,
                                               OT* C, int M, int N, int K, int gx) {
    __shared__ bf16 As[2 * 128 * 32];
    __shared__ bf16 Bs[2 * 128 * 32];
    const int tid = threadIdx.x;
    const int lane = tid & 63, wid = tid >> 6;
    const int l16 = lane & 15, quad = lane >> 4;
    const int wm = (wid >> 1) * 64, wn = (wid & 1) * 64;
    const int nwg = gridDim.x;
    const int wg = ((blockIdx.x & 7) * (nwg >> 3)) + (blockIdx.x >> 3);
    const int m0 = (wg / gx) * 128, n0 = (wg % gx) * 128;

    const int r0 = tid >> 2, sc0 = tid & 3;
    const int lc0 = sc0 ^ ((r0 >> 1) & 3);
    const int r1 = r0 + 64;
    const int lc1 = sc0 ^ ((r1 >> 1) & 3);
    const bf16* gA0 = A + (size_t)(m0 + r0) * K + lc0 * 8;
    const bf16* gA1 = A + (size_t)(m0 + r1) * K + lc1 * 8;
    const bf16* gB0 = B + (size_t)(n0 + r0) * ldB + lc0 * 8;
    const bf16* gB1 = B + (size_t)(n0 + r1) * ldB + lc1 * 8;
    char* asb = (char*)As;
    char* bsb = (char*)Bs;
    const int lb0 = wid * 1024, lb1 = 4096 + wid * 1024;  // wave-uniform bases
    const int rdsw = (quad ^ ((l16 >> 1) & 3)) * 16;      // frag-read swizzle

    f32x4 acc[4][4] = {};
    const int nT = K >> 5;
    gload_lds16(gA0, asb + lb0);
    gload_lds16(gA1, asb + lb1);
    gload_lds16(gB0, bsb + lb0);
    gload_lds16(gB1, bsb + lb1);
    __syncthreads();
    for (int t = 0; t < nT; ++t) {
        const int cur = t & 1;
        if (t + 1 < nT) {   // prefetch next K-step into other buffer
            char* ab = asb + (cur ^ 1) * 8192;
            char* bb = bsb + (cur ^ 1) * 8192;
            const int ko = (t + 1) * 32;
            gload_lds16(gA0 + ko, ab + lb0);
            gload_lds16(gA1 + ko, ab + lb1);
            gload_lds16(gB0 + ko, bb + lb0);
            gload_lds16(gB1 + ko, bb + lb1);
        }
        const char* ar = asb + cur * 8192;
        const char* br = bsb + cur * 8192;
        bf16x8 a[4], b[4];
#pragma unroll
        for (int i = 0; i < 4; ++i)
            a[i] = *(const bf16x8*)(ar + (wm + i * 16 + l16) * 64 + rdsw);
#pragma unroll
        for (int i = 0; i < 4; ++i)
            b[i] = *(const bf16x8*)(br + (wn + i * 16 + l16) * 64 + rdsw);
        __builtin_amdgcn_s_setprio(1);
#pragma unroll
        for (int mi = 0; mi < 4; ++mi)
#pragma unroll
            for (int ni = 0; ni < 4; ++ni)
                acc[mi][ni] = __builtin_amdgcn_mfma_f32_16x16x32_bf16(
                    a[mi], b[ni], acc[mi][ni], 0, 0, 0);
        __builtin_amdgcn_s_setprio(0);
        __syncthreads();   // drains prefetch (flew during compute) + lgkm
    }
#pragma unroll
    for (int mi = 0; mi < 4; ++mi) {
#pragma unroll
        for (int ni = 0; ni < 4; ++ni) {
            const int col = n0 + wn + ni * 16 + l16;
            const float bv = bias ? bias[col] : 0.f;
#pragma unroll
            for (int r = 0; r < 4; ++r) {
                const int row = m0 + wm + mi * 16 + quad * 4 + r;
                float val = acc[mi][ni][r] + bv;
                if (GELU) {
                    float z = 0.7978845608028654f * (val + 0.044715f * val * val * val);
                    float th = 1.f - 2.f / (__expf(2.f * z) + 1.f);
                    val = 0.5f * val * (1.f + th);
                }
                const size_t idx = (size_t)row * N + col;
                if (RES) val += toF(resid[idx]);
                if (ACC) val += toF(C[idx]);
                storeO(&C[idx], val);
            }
        }
    }
}

// ---------------------------------------------------------------- attention
// MFMA flash attention, register-staged K/V prefetch (T14), defer-max (T13),
// setprio (T5). 1-D grid 512: blocks c and c+256 (which land on the same CU
// under round-robin placement) get COMPLEMENTARY causal lengths (qi, 3-qi)
// so every CU's workload is ~equal (24 tile-iters). q,k,v rows stride rs
// (packed qkv [8192][3072]); o stride 1024.
__global__ __launch_bounds__(256) void attn_k(const bf16* __restrict__ q,
                                              const bf16* __restrict__ k,
                                              const bf16* __restrict__ v,
                                              bf16* __restrict__ o, int rs) {
    const int bid = blockIdx.x;
    const int u = bid & 255, top = bid >> 8;
    const int xx = u & 3;
    const int h = (u >> 2) & 15;
    const int b = top * 4 + (u >> 6);
    const int qi = top ? 3 - xx : xx;
    const int qblock = qi * 256;
    const int tid = threadIdx.x;
    const int wave = tid >> 6, lane = tid & 63;
    const int l16 = lane & 15, quad = lane >> 4;
    const int q0w = qblock + wave * 64;

    __shared__ __align__(16) bf16 Kl[64 * 64];       // [k][d] swizzled
    __shared__ __align__(16) bf16 Vt[64 * 64];       // [d][k] swizzled
    __shared__ __align__(16) bf16 Pl[4 * 64 * 64];   // per-wave [q][k] swizzled
    __shared__ __align__(16) float sc[4][64];        // per-wave per-q scratch

    bf16x8 qf[4][2];
#pragma unroll
    for (int ni = 0; ni < 4; ++ni) {
        const int row = q0w + ni * 16 + l16;
        const bf16* qp = q + ((size_t)b * 1024 + row) * rs + h * 64;
#pragma unroll
        for (int kc = 0; kc < 2; ++kc)
            qf[ni][kc] = *(const bf16x8*)(qp + kc * 32 + quad * 8);
    }

    f32x4 acc[4][4] = {};     // O: row q = mi*16+quad*4+r, col d = ni*16+l16
    float mrun[4], lrun[4];
#pragma unroll
    for (int ni = 0; ni < 4; ++ni) { mrun[ni] = -1e30f; lrun[ni] = 0.f; }

    const int NT = qi * 4 + 4;
    const int myNT = qi * 4 + wave + 1;

    const int kr_ = tid >> 3, kch = tid & 7;              // K rows kr_, kr_+32
    const int vr_ = (tid >> 3) * 2, vdb = (tid & 7) * 8;  // V rows vr_, vr_+1
    uint4 kA, kB, vA, vB;
    {   // prefetch tile 0
        const size_t gk = ((size_t)b * 1024 + 0 + kr_) * rs + h * 64 + kch * 8;
        kA = *(const uint4*)(k + gk);
        kB = *(const uint4*)(k + gk + (size_t)32 * rs);
        const size_t gv = ((size_t)b * 1024 + 0 + vr_) * rs + h * 64 + vdb;
        vA = *(const uint4*)(v + gv);
        vB = *(const uint4*)(v + gv + rs);
    }

    for (int t = 0; t < NT; ++t) {
        wgbar();   // all waves done reading Kl/Vt from previous tile
        // ---- write prefetched K (row-major, swizzled) ----
        *(uint4*)((char*)Kl + swzb(kr_, kch * 16)) = kA;
        *(uint4*)((char*)Kl + swzb(kr_ + 32, kch * 16)) = kB;
        // ---- write prefetched V transposed (Vt[d][k], swizzled) ----
        {
            const unsigned aw[4] = {vA.x, vA.y, vA.z, vA.w};
            const unsigned bw[4] = {vB.x, vB.y, vB.z, vB.w};
#pragma unroll
            for (int j = 0; j < 8; ++j) {
                const unsigned lo = (aw[j >> 1] >> ((j & 1) * 16)) & 0xffffu;
                const unsigned hi = (bw[j >> 1] >> ((j & 1) * 16)) & 0xffffu;
                *(unsigned*)((char*)Vt + swzb(vdb + j, vr_ * 2)) = lo | (hi << 16);
            }
        }
        // ---- issue next tile's global loads (fly across compute) ----
        if (t + 1 < NT) {
            const int j1 = (t + 1) * 64;
            const size_t gk = ((size_t)b * 1024 + j1 + kr_) * rs + h * 64 + kch * 8;
            kA = *(const uint4*)(k + gk);
            kB = *(const uint4*)(k + gk + (size_t)32 * rs);
            const size_t gv = ((size_t)b * 1024 + j1 + vr_) * rs + h * 64 + vdb;
            vA = *(const uint4*)(v + gv);
            vB = *(const uint4*)(v + gv + rs);
        }
        wgbar();   // staged tile visible to all waves
        if (t < myNT) {
            const int j0 = t * 64;
            // ---- S^T = K @ Q^T ----
            f32x4 st[4][4] = {};
#pragma unroll
            for (int kc = 0; kc < 2; ++kc) {
                bf16x8 kf[4];
#pragma unroll
                for (int mi = 0; mi < 4; ++mi)
                    kf[mi] = *(const bf16x8*)((char*)Kl +
                             swzb(mi * 16 + l16, kc * 64 + quad * 16));
                __builtin_amdgcn_s_setprio(1);
#pragma unroll
                for (int mi = 0; mi < 4; ++mi)
#pragma unroll
                    for (int ni = 0; ni < 4; ++ni)
                        st[mi][ni] = __builtin_amdgcn_mfma_f32_16x16x32_bf16(
                            kf[mi], qf[ni][kc], st[mi][ni], 0, 0, 0);
                __builtin_amdgcn_s_setprio(0);
            }
            if (j0 == q0w) {  // causal mask, diagonal tile only
#pragma unroll
                for (int mi = 0; mi < 4; ++mi)
#pragma unroll
                    for (int ni = 0; ni < 4; ++ni)
#pragma unroll
                        for (int r = 0; r < 4; ++r)
                            if (mi * 16 + quad * 4 + r > ni * 16 + l16)
                                st[mi][ni][r] = -1e30f;
            }
            // ---- tile max per q (tree + cross-quad reduce) ----
            float mx[4];
#pragma unroll
            for (int ni = 0; ni < 4; ++ni) {
                float a0 = fmaxf(st[0][ni][0], st[0][ni][1]);
                float a1 = fmaxf(st[0][ni][2], st[0][ni][3]);
                float a2 = fmaxf(st[1][ni][0], st[1][ni][1]);
                float a3 = fmaxf(st[1][ni][2], st[1][ni][3]);
                float a4 = fmaxf(st[2][ni][0], st[2][ni][1]);
                float a5 = fmaxf(st[2][ni][2], st[2][ni][3]);
                float a6 = fmaxf(st[3][ni][0], st[3][ni][1]);
                float a7 = fmaxf(st[3][ni][2], st[3][ni][3]);
                float m_ = fmaxf(fmaxf(fmaxf(a0, a1), fmaxf(a2, a3)),
                                 fmaxf(fmaxf(a4, a5), fmaxf(a6, a7)));
                m_ = fmaxf(m_, __shfl_xor(m_, 16, 64));
                m_ = fmaxf(m_, __shfl_xor(m_, 32, 64));
                mx[ni] = m_;
            }
            // ---- defer-max (T13): rescale only if growth > 64 raw (=8
            // scaled); P then bounded by e^8, safe in bf16/fp32. ----
            const bool need = (mx[0] > mrun[0] + 64.f) | (mx[1] > mrun[1] + 64.f) |
                              (mx[2] > mrun[2] + 64.f) | (mx[3] > mrun[3] + 64.f);
            if (__any(need)) {
                float fac[4];
#pragma unroll
                for (int ni = 0; ni < 4; ++ni) {
                    const float nm = (mx[ni] > mrun[ni] + 64.f) ? mx[ni] : mrun[ni];
                    fac[ni] = __expf((mrun[ni] - nm) * 0.125f);
                    mrun[ni] = nm;
                    lrun[ni] *= fac[ni];
                }
                if (quad == 0)
#pragma unroll
                    for (int ni = 0; ni < 4; ++ni) sc[wave][ni * 16 + l16] = fac[ni];
#pragma unroll
                for (int mi = 0; mi < 4; ++mi) {
                    const f32x4 f4 = *(const f32x4*)&sc[wave][mi * 16 + quad * 4];
#pragma unroll
                    for (int ni = 0; ni < 4; ++ni)
#pragma unroll
                        for (int r = 0; r < 4; ++r) acc[mi][ni][r] *= f4[r];
                }
            }
            // ---- exp + sum (4 parallel chains, tree finish) ----
#pragma unroll
            for (int ni = 0; ni < 4; ++ni) {
                const float mm = mrun[ni];
                float t0 = 0.f, t1 = 0.f, t2 = 0.f, t3 = 0.f;
#pragma unroll
                for (int mi = 0; mi < 4; ++mi) {
                    float p0 = __expf((st[mi][ni][0] - mm) * 0.125f);
                    float p1 = __expf((st[mi][ni][1] - mm) * 0.125f);
                    float p2 = __expf((st[mi][ni][2] - mm) * 0.125f);
                    float p3 = __expf((st[mi][ni][3] - mm) * 0.125f);
                    st[mi][ni][0] = p0; st[mi][ni][1] = p1;
                    st[mi][ni][2] = p2; st[mi][ni][3] = p3;
                    t0 += p0; t1 += p1; t2 += p2; t3 += p3;
                }
                float ls = (t0 + t1) + (t2 + t3);
                ls += __shfl_xor(ls, 16, 64);
                ls += __shfl_xor(ls, 32, 64);
                lrun[ni] += ls;
            }
            // ---- write P to per-wave LDS [q][k] (b64 packed, swizzled) ----
            char* Pb = (char*)Pl + wave * 8192;
#pragma unroll
            for (int ni = 0; ni < 4; ++ni) {
                const int qrow = ni * 16 + l16;
#pragma unroll
                for (int mi = 0; mi < 4; ++mi) {
                    union { bf16 bv[4]; uint2 u2; } pk;
#pragma unroll
                    for (int r = 0; r < 4; ++r)
                        pk.bv[r] = __float2bfloat16(st[mi][ni][r]);
                    *(uint2*)(Pb + swzb(qrow, mi * 32 + quad * 8)) = pk.u2;
                }
            }
            // ---- O += P @ V ----
#pragma unroll
            for (int kc = 0; kc < 2; ++kc) {
                bf16x8 pf[4], vf[4];
#pragma unroll
                for (int mi = 0; mi < 4; ++mi)
                    pf[mi] = *(const bf16x8*)(Pb +
                             swzb(mi * 16 + l16, kc * 64 + quad * 16));
#pragma unroll
                for (int ni = 0; ni < 4; ++ni)
                    vf[ni] = *(const bf16x8*)((char*)Vt +
                             swzb(ni * 16 + l16, kc * 64 + quad * 16));
                __builtin_amdgcn_s_setprio(1);
#pragma unroll
                for (int mi = 0; mi < 4; ++mi)
#pragma unroll
                    for (int ni = 0; ni < 4; ++ni)
                        acc[mi][ni] = __builtin_amdgcn_mfma_f32_16x16x32_bf16(
                            pf[mi], vf[ni], acc[mi][ni], 0, 0, 0);
                __builtin_amdgcn_s_setprio(0);
            }
        }
    }
    if (quad == 0)
#pragma unroll
        for (int ni = 0; ni < 4; ++ni) sc[wave][ni * 16 + l16] = lrun[ni];
#pragma unroll
    for (int mi = 0; mi < 4; ++mi) {
        const f32x4 l4 = *(const f32x4*)&sc[wave][mi * 16 + quad * 4];
#pragma unroll
        for (int r = 0; r < 4; ++r) {
            const float inv = 1.f / l4[r];
            const int row = q0w + mi * 16 + quad * 4 + r;
            bf16* orow = o + ((size_t)b * 1024 + row) * 1024 + h * 64;
#pragma unroll
            for (int ni = 0; ni < 4; ++ni)
                orow[ni * 16 + l16] = __float2bfloat16(acc[mi][ni][r] * inv);
        }
    }
}

// ---------------------------------------------------------------- launch
extern "C" void kernel_launch(void* const* d_in, const int* in_sizes, int n_in,
                              void* d_out, int out_size, void* d_ws, size_t ws_size,
                              hipStream_t stream) {
    (void)out_size; (void)ws_size;
    const float* x = (const float*)d_in[0];
    const int base = (n_in >= 18 && in_sizes[1] > 4096) ? 2 : 1;  // skip mask
    const float* ln1s = (const float*)d_in[base + 0];
    const float* ln1b = (const float*)d_in[base + 1];
    const float* wq   = (const float*)d_in[base + 2];
    const float* bq   = (const float*)d_in[base + 3];
    const float* wk   = (const float*)d_in[base + 4];
    const float* bk   = (const float*)d_in[base + 5];
    const float* wv   = (const float*)d_in[base + 6];
    const float* bv   = (const float*)d_in[base + 7];
    const float* wo   = (const float*)d_in[base + 8];
    const float* bo   = (const float*)d_in[base + 9];
    const float* ln2s = (const float*)d_in[base + 10];
    const float* ln2b = (const float*)d_in[base + 11];
    const float* w1   = (const float*)d_in[base + 12];
    const float* b1   = (const float*)d_in[base + 13];
    const float* w2   = (const float*)d_in[base + 14];
    const float* b2   = (const float*)d_in[base + 15];
    float* out = (float*)d_out;   // fp32 output (also used as scratch)

    // Workspace map (64MB), phase-disjoint lifetimes:
    //   ws[0,16)  h (LN1) -> ao (attn out) -> h2 (LN2 out)
    //   ws[16,64) qkv [8192][3072] bf16 -> woT[16,18) -> f1c[16,48)
    //   ws[48,56) w1T  (after attn)      ws[56,64) w2T
    // d_out (32MB fp32) as scratch early:
    //   out[0,6MB) wqkvT bf16 [3072][1024]; out[8MB) bqkv [3072] fp32
    //   -> x2 fp32 (wo GEMM, residual) -> final output (FFN2 ACC)
    char* ws = (char*)d_ws;
    char* oc = (char*)d_out;
    const size_t MB = 1ull << 20;
    bf16* h     = (bf16*)(ws + 0 * MB);
    bf16* qkv   = (bf16*)(ws + 16 * MB);
    bf16* ao    = (bf16*)(ws + 0 * MB);
    bf16* h2    = (bf16*)(ws + 0 * MB);
    bf16* woT   = (bf16*)(ws + 16 * MB);
    bf16* f1c   = (bf16*)(ws + 16 * MB);   // [8192][2048] bf16, 32MB
    bf16* w1T   = (bf16*)(ws + 48 * MB);
    bf16* w2T   = (bf16*)(ws + 56 * MB);
    bf16* wqkvT = (bf16*)(oc + 0 * MB);
    float* bqkv = (float*)(oc + 8 * MB);

    const dim3 tb(256);

    layernorm_k<float><<<8192, tb, 0, stream>>>(x, ln1s, ln1b, h);
    transpose_k<<<dim3(32, 32), tb, 0, stream>>>(wq, wqkvT, 1024, 1024);
    transpose_k<<<dim3(32, 32), tb, 0, stream>>>(wk, wqkvT + 1024 * 1024, 1024, 1024);
    transpose_k<<<dim3(32, 32), tb, 0, stream>>>(wv, wqkvT + 2 * 1024 * 1024, 1024, 1024);
    catb_k<<<12, tb, 0, stream>>>(bq, bk, bv, bqkv);
    // fused QKV: [8192][3072] = h @ wqkvT   (grid 1536, gx=24)
    mgemm_k<0, 0, 0, float, bf16><<<1536, tb, 0, stream>>>(
        h, wqkvT, 1024, bqkv, nullptr, qkv, 8192, 3072, 1024, 24);
    attn_k<<<512, tb, 0, stream>>>(qkv, qkv + 1024, qkv + 2048, ao, 3072);
    // qkv dead: transpose remaining weights
    transpose_k<<<dim3(32, 32), tb, 0, stream>>>(wo, woT, 1024, 1024);
    transpose_k<<<dim3(128, 32), tb, 0, stream>>>(w1, w1T, 1024, 4096);
    transpose_k<<<dim3(32, 128), tb, 0, stream>>>(w2, w2T, 4096, 1024);
    // x2 = ao @ woT + bo + x  -> fp32 directly into out (residual stream)
    mgemm_k<0, 1, 0, float, float><<<512, tb, 0, stream>>>(
        ao, woT, 1024, bo, x, out, 8192, 1024, 1024, 8);
    layernorm_k<float><<<8192, tb, 0, stream>>>(out, ln2s, ln2b, h2);
    // FFN in 2 chunks of 2048; FFN2 accumulates onto out (holds x2)
    for (int c = 0; c < 2; ++c) {
        mgemm_k<1, 0, 0, float, bf16><<<1024, tb, 0, stream>>>(
            h2, w1T + (size_t)c * 2048 * 1024, 1024, b1 + c * 2048, nullptr,
            f1c, 8192, 2048, 1024, 16);
        mgemm_k<0, 0, 1, float, float><<<512, tb, 0, stream>>>(
            f1c, w2T + c * 2048, 4096, c ? nullptr : b2, nullptr,
            out, 8192, 1024, 2048, 8);
    }
}